// Round 13
// baseline (113.803 us; speedup 1.0000x reference)
//
#include <hip/hip_runtime.h>
#include <hip/hip_bf16.h>
#include <stdint.h>

#define N_PTS   4096
#define M_CODES 4096
#define ZDIM    1024
#define KG      (ZDIM / 8)          // 128 k-groups of 8 elements
// Tiled bf16 layout: elem (r,k) at seg(rb)*16384 + kg*128 + r16*8 + ke
//   rb=r>>4, r16=r&15, kg=k>>3, ke=k&7. Chunk (rb,kg) = 16 rows x 8 k = 256 B.
// K-slice sl (K=32): element offset sl*512 within a segment.

typedef __attribute__((ext_vector_type(8))) short bf16x8;
typedef __attribute__((ext_vector_type(4))) float f32x4;

__device__ __forceinline__ unsigned short f2bf(float f) {
    __hip_bfloat16 h = __float2bfloat16(f);
    return *reinterpret_cast<unsigned short*>(&h);
}
__device__ __forceinline__ unsigned enc_f32(float f) {
    unsigned u = __float_as_uint(f);
    return (u & 0x80000000u) ? ~u : (u | 0x80000000u);
}
__device__ __forceinline__ float dec_f32(unsigned e) {
    unsigned u = (e & 0x80000000u) ? (e ^ 0x80000000u) : ~u;
    return __uint_as_float(u);
}

// ---------------------------------------------------------------------------
// prep: fp32 -> bf16 + TILED layout + row sum-of-squares (R11, unchanged).
// ---------------------------------------------------------------------------
#define PREP_PITCH 1032   // ushorts per LDS row: 1024 + 8 pad (16 B-aligned)
__global__ __launch_bounds__(256) void prep_kernel(
    const float* __restrict__ z, const float* __restrict__ e,
    unsigned short* __restrict__ zb, unsigned short* __restrict__ eb,
    float* __restrict__ zsq, float* __restrict__ esq,
    unsigned* __restrict__ min_enc) {
    __shared__ unsigned short tile[16 * PREP_PITCH];  // ~33 KB
    __shared__ float redbuf[4 * 16];

    const int t = threadIdx.x;
    const int b = blockIdx.x;
    if (b < 16) min_enc[b * 256 + t] = 0xFFFFFFFFu;

    const bool is_z = b < 256;
    const int rb = b & 255;
    const float* src = (is_z ? z : e) + (size_t)rb * 16 * ZDIM;
    unsigned short* dst = (is_z ? zb : eb) + (size_t)rb * 16384;  // 32 KB seg
    const int w = t >> 6, lane = t & 63;

    #pragma unroll
    for (int it = 0; it < 16; it++) {
        float4 v = reinterpret_cast<const float4*>(src + (size_t)it * ZDIM)[t];
        ushort4 o;
        o.x = f2bf(v.x); o.y = f2bf(v.y); o.z = f2bf(v.z); o.w = f2bf(v.w);
        *reinterpret_cast<ushort4*>(&tile[it * PREP_PITCH + t * 4]) = o;
    }
    __syncthreads();

    float s = 0.f;
    #pragma unroll
    for (int it2 = 0; it2 < 8; it2++) {
        const int c = it2 * 256 + t;          // 0..2047
        const int kg = c >> 4, r16 = c & 15;  // r16 == t&15 (thread-constant)
        bf16x8 val = *reinterpret_cast<const bf16x8*>(
            &tile[r16 * PREP_PITCH + kg * 8]);
        *reinterpret_cast<bf16x8*>(&dst[(size_t)c * 8]) = val;
        #pragma unroll
        for (int j = 0; j < 8; j++) {
            float f = __uint_as_float(((unsigned)(unsigned short)val[j]) << 16);
            s = fmaf(f, f, s);
        }
    }
    s += __shfl_xor(s, 16, 64);
    s += __shfl_xor(s, 32, 64);
    if (lane < 16) redbuf[w * 16 + lane] = s;
    __syncthreads();
    if (t < 16) {
        float sq = redbuf[t] + redbuf[16 + t] + redbuf[32 + t] + redbuf[48 + t];
        const int row = rb * 16 + t;
        if (is_z) zsq[row] = sq; else esq[row] = sq;
    }
}

// ---------------------------------------------------------------------------
// gemm_min: R12 single-barrier double-buffered A-DMA pipeline + NEW:
// B register prefetch one K=32 slice ahead. The B loads for slice sl+1
// issue while slice sl's 16 MFMAs execute; when a prefetch crosses a
// barrier, the barrier's implicit vmcnt(0) simply DRAINS it into registers
// (completion, not discard) — its L2 latency lands under compute instead of
// in front of the MFMAs. Live regs ~124 <= 128 -> 4 blocks/CU held.
// A through LDS (shared across wn waves), B direct from global (R10).
// 256 thr = 4 waves (2x2 of 64x64), grid (32,32).
// ---------------------------------------------------------------------------
__global__ __launch_bounds__(256, 4) void gemm_min_kernel(
    const unsigned short* __restrict__ zb, const unsigned short* __restrict__ eb,
    const float* __restrict__ zsq, unsigned* __restrict__ min_enc) {
    __shared__ __align__(16) unsigned short As[16384];  // 2 x 16 KB
    __shared__ float zsq_s[128];
    __shared__ float colmin[2][128];

    const int t = threadIdx.x;        // 0..255
    const int bx = blockIdx.x;        // code (col) block
    const int by = blockIdx.y;        // point (row) block
    const int lane = t & 63;
    const int w = t >> 6;             // 0..3
    const int wm = w >> 1, wn = w & 1;
    const int lrow = lane & 15;
    const int q = lane >> 4;

    if (t < 128) zsq_s[t] = zsq[by * 128 + t];

    f32x4 acc[4][4];
    #pragma unroll
    for (int i = 0; i < 4; i++)
        #pragma unroll
        for (int j = 0; j < 4; j++) acc[i][j] = (f32x4){0.f, 0.f, 0.f, 0.f};

    // A staging geometry (R10-proven): instr j covers 4 KB = 2 segs' 2 KB
    // runs; global addr is lane-linear 16 B within each wave.
    const int seg_half = t >> 7;            // 0..1
    const int inner = (t & 127) * 8;        // element offset in 2 KB run
    const int lds_w = w * 512;              // wave-uniform (elements)
    const size_t a_seg0 = (size_t)(by * 8) * 16384;

    // B fragment base: lane addr = lane*8 (lane-linear 1 KB per fragment).
    const unsigned short* b_base =
        eb + (size_t)(bx * 8 + wn * 4) * 16384 + lane * 8;

#define DMA_STAGE(st_)                                                        \
    {                                                                         \
        const int buf_ = ((st_) & 1) * 8192;                                  \
        const int koff_ = (st_) * 1024;                                       \
        _Pragma("unroll")                                                     \
        for (int j = 0; j < 4; j++) {                                         \
            const unsigned short* ga = zb + a_seg0 +                          \
                (size_t)(j * 2 + seg_half) * 16384 + koff_ + inner;           \
            __builtin_amdgcn_global_load_lds(                                 \
                (const __attribute__((address_space(1))) void*)ga,            \
                (__attribute__((address_space(3))) void*)(As + buf_ +         \
                    j * 2048 + lds_w), 16, 0, 0);                             \
        }                                                                     \
    }

    // Preload B slice 0 into registers.
    bf16x8 bb_cur[4];
    #pragma unroll
    for (int an = 0; an < 4; an++)
        bb_cur[an] = *(const bf16x8*)(b_base + (size_t)an * 16384);

    DMA_STAGE(0);
    for (int st = 0; st < 16; st++) {
        __syncthreads();                 // drains DMA(st) + in-flight B prefetch
        if (st < 15) DMA_STAGE(st + 1);  // overlaps with compute(st)
        const int buf = (st & 1) * 8192;
        #pragma unroll
        for (int s = 0; s < 2; s++) {    // two K=32 slices
            const int sl = st * 2 + s;
            const int nsl = (sl < 31) ? sl + 1 : 31;  // clamp: tail reload, harmless
            // Prefetch B(sl+1) FIRST so its latency overlaps this slice's MFMAs.
            bf16x8 bb_next[4];
            #pragma unroll
            for (int an = 0; an < 4; an++)
                bb_next[an] = *(const bf16x8*)(b_base + (size_t)an * 16384 +
                                               (size_t)nsl * 512);
            bf16x8 a[4];
            #pragma unroll
            for (int am = 0; am < 4; am++)
                a[am] = *(const bf16x8*)(As + buf + (wm * 4 + am) * 1024 +
                                         s * 512 + lane * 8);
            #pragma unroll
            for (int am = 0; am < 4; am++)
                #pragma unroll
                for (int an = 0; an < 4; an++)
                    acc[am][an] = __builtin_amdgcn_mfma_f32_16x16x32_bf16(
                        a[am], bb_cur[an], acc[am][an], 0, 0, 0);
            #pragma unroll
            for (int an = 0; an < 4; an++) bb_cur[an] = bb_next[an];
        }
    }
#undef DMA_STAGE

    __syncthreads();

    // Epilogue (R5/R6-proven). C/D layout: row = q*4+r, col = lrow.
    #pragma unroll
    for (int an = 0; an < 4; an++) {
        float v = 3.4e38f;
        #pragma unroll
        for (int am = 0; am < 4; am++) {
            const int rbase = wm * 64 + am * 16 + q * 4;
            f32x4 c = acc[am][an];
            v = fminf(v, zsq_s[rbase + 0] - 2.f * c[0]);
            v = fminf(v, zsq_s[rbase + 1] - 2.f * c[1]);
            v = fminf(v, zsq_s[rbase + 2] - 2.f * c[2]);
            v = fminf(v, zsq_s[rbase + 3] - 2.f * c[3]);
        }
        v = fminf(v, __shfl_xor(v, 16, 64));
        v = fminf(v, __shfl_xor(v, 32, 64));
        if (q == 0) colmin[wm][wn * 64 + an * 16 + lrow] = v;
    }
    __syncthreads();
    if (t < 128) {
        const float m = fminf(colmin[0][t], colmin[1][t]);
        atomicMin(&min_enc[bx * 128 + t], enc_f32(m));
    }
}

// ---------------------------------------------------------------------------
// finalize: mean_j (dec(min_enc[j]) + esq[j]) -> single fp32 scalar.
// ---------------------------------------------------------------------------
__global__ __launch_bounds__(256) void finalize_kernel(
    const unsigned* __restrict__ min_enc, const float* __restrict__ esq,
    float* __restrict__ out) {
    const int t = threadIdx.x;
    float s = 0.f;
    #pragma unroll
    for (int i = 0; i < M_CODES / 256; i++) {
        const int j = i * 256 + t;
        s += dec_f32(min_enc[j]) + esq[j];
    }
    #pragma unroll
    for (int off = 1; off < 64; off <<= 1) s += __shfl_xor(s, off, 64);
    __shared__ float red[4];
    if ((t & 63) == 0) red[t >> 6] = s;
    __syncthreads();
    if (t == 0) out[0] = (red[0] + red[1] + red[2] + red[3]) * (1.f / M_CODES);
}

extern "C" void kernel_launch(void* const* d_in, const int* in_sizes, int n_in,
                              void* d_out, int out_size, void* d_ws, size_t ws_size,
                              hipStream_t stream) {
    (void)in_sizes; (void)n_in; (void)out_size; (void)ws_size;
    const float* z = (const float*)d_in[0];
    const float* e = (const float*)d_in[1];
    char* ws = (char*)d_ws;
    unsigned short* zb = (unsigned short*)ws;                            // 8 MB
    unsigned short* eb = (unsigned short*)(ws + ((size_t)8 << 20));      // 8 MB
    float* zsq = (float*)(ws + ((size_t)16 << 20));                      // 16 KB
    float* esq = (float*)(ws + ((size_t)16 << 20) + 16384);              // 16 KB
    unsigned* min_enc = (unsigned*)(ws + ((size_t)16 << 20) + 32768);    // 16 KB

    prep_kernel<<<dim3(512), dim3(256), 0, stream>>>(
        z, e, zb, eb, zsq, esq, min_enc);
    gemm_min_kernel<<<dim3(32, 32), dim3(256), 0, stream>>>(
        zb, eb, zsq, min_enc);
    finalize_kernel<<<dim3(1), dim3(256), 0, stream>>>(min_enc, esq, (float*)d_out);
}

// Round 14
// 112.063 us; speedup vs baseline: 1.0155x; 1.0155x over previous
//
#include <hip/hip_runtime.h>
#include <hip/hip_bf16.h>
#include <stdint.h>

#define N_PTS   4096
#define M_CODES 4096
#define ZDIM    1024
// fp8 tiled layout: elem (r,k) at seg(rb)*16384 + kg*128 + r16*8 + ke  (BYTES)
//   rb=r>>4, r16=r&15, kg=k>>3, ke=k&7. Chunk (rb,kg) = 16 rows x 8 k = 128 B.
//   Seg = 16 rows x 1024 k x 1 B = 16 KB.

typedef __attribute__((ext_vector_type(4))) float f32x4;

__device__ __forceinline__ unsigned enc_f32(float f) {
    unsigned u = __float_as_uint(f);
    return (u & 0x80000000u) ? ~u : (u | 0x80000000u);
}
__device__ __forceinline__ float dec_f32(unsigned e) {
    unsigned u = (e & 0x80000000u) ? (e ^ 0x80000000u) : ~u;
    return __uint_as_float(u);
}

// ---------------------------------------------------------------------------
// prep: fp32 -> fp8 e4m3 (OCP) + tiled layout + row sum-of-squares (fp32,
// pre-quantization — error enters as 2(e.dz+z.de), sigma~2 << 35.5 threshold).
// One block = 16 rows. grid 512 (256 z + 256 e).
// ---------------------------------------------------------------------------
#define PREP_PITCH_B 1040   // bytes per LDS row: 1024 + 16 pad
__global__ __launch_bounds__(256) void prep_kernel(
    const float* __restrict__ z, const float* __restrict__ e,
    uint8_t* __restrict__ zb, uint8_t* __restrict__ eb,
    float* __restrict__ zsq, float* __restrict__ esq,
    unsigned* __restrict__ min_enc) {
    __shared__ uint8_t tile[16 * PREP_PITCH_B];   // ~16.6 KB
    __shared__ float redbuf[16 * 4];

    const int t = threadIdx.x;
    const int b = blockIdx.x;
    if (b < 16) min_enc[b * 256 + t] = 0xFFFFFFFFu;

    const bool is_z = b < 256;
    const int rb = b & 255;
    const float* src = (is_z ? z : e) + (size_t)rb * 16 * ZDIM;
    uint8_t* dst = (is_z ? zb : eb) + (size_t)rb * 16384;   // 16 KB seg
    const int w = t >> 6, lane = t & 63;

    // Phase 1: coalesced loads, fp32 row sums (R8-proven reduction),
    // pack 4 floats -> 4 fp8 into one dword in LDS.
    #pragma unroll
    for (int it = 0; it < 16; it++) {
        float4 v = reinterpret_cast<const float4*>(src + (size_t)it * ZDIM)[t];
        int pk = 0;
        pk = __builtin_amdgcn_cvt_pk_fp8_f32(v.x, v.y, pk, false);
        pk = __builtin_amdgcn_cvt_pk_fp8_f32(v.z, v.w, pk, true);
        *reinterpret_cast<int*>(&tile[it * PREP_PITCH_B + t * 4]) = pk;
        float s = v.x * v.x + v.y * v.y + v.z * v.z + v.w * v.w;
        #pragma unroll
        for (int off = 1; off < 64; off <<= 1) s += __shfl_xor(s, off, 64);
        if (lane == 0) redbuf[it * 4 + w] = s;
    }
    __syncthreads();

    // Phase 2: transpose-store to tiled global (chunk c -> dst + c*8, linear).
    #pragma unroll
    for (int it2 = 0; it2 < 8; it2++) {
        const int c = it2 * 256 + t;          // 0..2047
        const int kg = c >> 4, r16 = c & 15;
        const unsigned long long val = *reinterpret_cast<const unsigned long long*>(
            &tile[r16 * PREP_PITCH_B + kg * 8]);
        *reinterpret_cast<unsigned long long*>(&dst[(size_t)c * 8]) = val;
    }
    if (t < 16) {
        float sq = redbuf[t * 4] + redbuf[t * 4 + 1] +
                   redbuf[t * 4 + 2] + redbuf[t * 4 + 3];
        const int row = rb * 16 + t;
        if (is_z) zsq[row] = sq; else esq[row] = sq;
    }
}

// ---------------------------------------------------------------------------
// gemm_min (fp8): R12 champion structure with all byte-terms halved.
// Single-barrier double-buffered A-DMA pipeline, K-stage=128 (8 stages,
// 8 barriers, 64 MFMA/barrier/wave). A via LDS (ds_read_b64 at lane*8,
// 2-way bank alias = free), B direct from global (dwordx2 lane-linear).
// mfma_f32_16x16x32_fp8_fp8 (i64 operands), C/D layout shape-determined
// (same epilogue as bf16). 256 thr = 4 waves (2x2 of 64x64), grid (32,32),
// 4 blocks/CU.
// ---------------------------------------------------------------------------
__global__ __launch_bounds__(256, 4) void gemm_min_kernel(
    const uint8_t* __restrict__ zb, const uint8_t* __restrict__ eb,
    const float* __restrict__ zsq, unsigned* __restrict__ min_enc) {
    __shared__ __align__(16) uint8_t As[32768];  // 2 x 16 KB (8 segs x 2 KB)
    __shared__ float zsq_s[128];
    __shared__ float colmin[2][128];

    const int t = threadIdx.x;        // 0..255
    const int bx = blockIdx.x;        // code (col) block
    const int by = blockIdx.y;        // point (row) block
    const int lane = t & 63;
    const int w = t >> 6;             // 0..3
    const int wm = w >> 1, wn = w & 1;
    const int lrow = lane & 15;
    const int q = lane >> 4;

    if (t < 128) zsq_s[t] = zsq[by * 128 + t];

    f32x4 acc[4][4];
    #pragma unroll
    for (int i = 0; i < 4; i++)
        #pragma unroll
        for (int j = 0; j < 4; j++) acc[i][j] = (f32x4){0.f, 0.f, 0.f, 0.f};

    // A staging: per stage 16 KB (8 segs x 2 KB run). Instr j (0..3) = 4 KB:
    // waves {0,1} -> seg 2j, waves {2,3} -> seg 2j+1; inner = (t&127)*16.
    // LDS dest = buf + seg*2048 + (t&127)*16  (wave-uniform base + lane*16).
    const int seg_half = t >> 7;            // 0..1
    const int inner = (t & 127) * 16;       // byte offset in 2 KB run
    const size_t a_seg0 = (size_t)(by * 8) * 16384;

    // B base: lane byte addr = lane*8 (lane-linear 512 B per fragment read).
    const uint8_t* b_base =
        eb + (size_t)(bx * 8 + wn * 4) * 16384 + lane * 8;

#define DMA_STAGE(st_)                                                        \
    {                                                                         \
        const int buf_ = ((st_) & 1) * 16384;                                 \
        const int koff_ = (st_) * 2048;  /* byte offset within seg */         \
        _Pragma("unroll")                                                     \
        for (int j = 0; j < 4; j++) {                                         \
            const uint8_t* ga = zb + a_seg0 +                                 \
                (size_t)(j * 2 + seg_half) * 16384 + koff_ + inner;           \
            __builtin_amdgcn_global_load_lds(                                 \
                (const __attribute__((address_space(1))) void*)ga,            \
                (__attribute__((address_space(3))) void*)(As + buf_ +         \
                    (j * 2 + seg_half) * 2048 + inner), 16, 0, 0);            \
        }                                                                     \
    }

    DMA_STAGE(0);
    for (int st = 0; st < 8; st++) {
        __syncthreads();                 // drains DMA(st)
        if (st < 7) DMA_STAGE(st + 1);   // overlaps with compute(st)
        const int buf = (st & 1) * 16384;
        const int koff = st * 2048;
        #pragma unroll
        for (int sl = 0; sl < 4; sl++) {   // four K=32 slices
            long a[4], bb[4];
            #pragma unroll
            for (int an = 0; an < 4; an++)
                bb[an] = *(const long*)(b_base + (size_t)an * 16384 +
                                        koff + sl * 512);
            #pragma unroll
            for (int am = 0; am < 4; am++)
                a[am] = *(const long*)(As + buf + (wm * 4 + am) * 2048 +
                                       sl * 512 + lane * 8);
            #pragma unroll
            for (int am = 0; am < 4; am++)
                #pragma unroll
                for (int an = 0; an < 4; an++)
                    acc[am][an] = __builtin_amdgcn_mfma_f32_16x16x32_fp8_fp8(
                        a[am], bb[an], acc[am][an], 0, 0, 0);
        }
    }
#undef DMA_STAGE

    __syncthreads();

    // Epilogue (proven; C/D layout shape-determined): row = q*4+r, col = lrow.
    #pragma unroll
    for (int an = 0; an < 4; an++) {
        float v = 3.4e38f;
        #pragma unroll
        for (int am = 0; am < 4; am++) {
            const int rbase = wm * 64 + am * 16 + q * 4;
            f32x4 c = acc[am][an];
            v = fminf(v, zsq_s[rbase + 0] - 2.f * c[0]);
            v = fminf(v, zsq_s[rbase + 1] - 2.f * c[1]);
            v = fminf(v, zsq_s[rbase + 2] - 2.f * c[2]);
            v = fminf(v, zsq_s[rbase + 3] - 2.f * c[3]);
        }
        v = fminf(v, __shfl_xor(v, 16, 64));
        v = fminf(v, __shfl_xor(v, 32, 64));
        if (q == 0) colmin[wm][wn * 64 + an * 16 + lrow] = v;
    }
    __syncthreads();
    if (t < 128) {
        const float m = fminf(colmin[0][t], colmin[1][t]);
        atomicMin(&min_enc[bx * 128 + t], enc_f32(m));
    }
}

// ---------------------------------------------------------------------------
// finalize: mean_j (dec(min_enc[j]) + esq[j]) -> single fp32 scalar.
// ---------------------------------------------------------------------------
__global__ __launch_bounds__(256) void finalize_kernel(
    const unsigned* __restrict__ min_enc, const float* __restrict__ esq,
    float* __restrict__ out) {
    const int t = threadIdx.x;
    float s = 0.f;
    #pragma unroll
    for (int i = 0; i < M_CODES / 256; i++) {
        const int j = i * 256 + t;
        s += dec_f32(min_enc[j]) + esq[j];
    }
    #pragma unroll
    for (int off = 1; off < 64; off <<= 1) s += __shfl_xor(s, off, 64);
    __shared__ float red[4];
    if ((t & 63) == 0) red[t >> 6] = s;
    __syncthreads();
    if (t == 0) out[0] = (red[0] + red[1] + red[2] + red[3]) * (1.f / M_CODES);
}

extern "C" void kernel_launch(void* const* d_in, const int* in_sizes, int n_in,
                              void* d_out, int out_size, void* d_ws, size_t ws_size,
                              hipStream_t stream) {
    (void)in_sizes; (void)n_in; (void)out_size; (void)ws_size;
    const float* z = (const float*)d_in[0];
    const float* e = (const float*)d_in[1];
    char* ws = (char*)d_ws;
    uint8_t* zb = (uint8_t*)ws;                                          // 4 MB
    uint8_t* eb = (uint8_t*)(ws + ((size_t)4 << 20));                    // 4 MB
    float* zsq = (float*)(ws + ((size_t)8 << 20));                       // 16 KB
    float* esq = (float*)(ws + ((size_t)8 << 20) + 16384);               // 16 KB
    unsigned* min_enc = (unsigned*)(ws + ((size_t)8 << 20) + 32768);     // 16 KB

    prep_kernel<<<dim3(512), dim3(256), 0, stream>>>(
        z, e, zb, eb, zsq, esq, min_enc);
    gemm_min_kernel<<<dim3(32, 32), dim3(256), 0, stream>>>(
        zb, eb, zsq, min_enc);
    finalize_kernel<<<dim3(1), dim3(256), 0, stream>>>(min_enc, esq, (float*)d_out);
}